// Round 5
// baseline (170.296 us; speedup 1.0000x reference)
//
#include <hip/hip_runtime.h>

#define BN 4
#define NN 4096
#define SPLITK 4
#define KTILE 64
#define LOG2E 1.44269504f
#define MFIX 36.0f

typedef __attribute__((ext_vector_type(8))) __bf16 bf16x8;
typedef __attribute__((ext_vector_type(8))) short s16x8;
typedef __attribute__((ext_vector_type(4))) float f32x4;
typedef unsigned short u16;

__device__ __forceinline__ u16 f2bf(float x) {  // manual RNE
  unsigned int u = __builtin_bit_cast(unsigned int, x);
  u = (u + 0x7fffu + ((u >> 16) & 1u)) >> 16;
  return (u16)u;
}
__device__ __forceinline__ u16 f2bfs(float x) {  // hw cvt path
  __bf16 b = (__bf16)x;
  return __builtin_bit_cast(u16, b);
}
__device__ __forceinline__ float bf2f(u16 s) {
  unsigned int u = ((unsigned int)s) << 16;
  return __builtin_bit_cast(float, u);
}

// raw v_exp_f32 (no denormal-fixup sequence). Inputs in [-100, 0].
__device__ __forceinline__ float fexp2(float x) {
#if defined(__HIP_DEVICE_COMPILE__) && __has_builtin(__builtin_amdgcn_exp2f)
  return __builtin_amdgcn_exp2f(x);
#else
  return __builtin_exp2f(x);
#endif
}

// v_mfma_f32_16x16x32_bf16 (native K=32 pipe)
__device__ __forceinline__ f32x4 mfma32(bf16x8 a, bf16x8 b, f32x4 c) {
#if defined(__HIP_DEVICE_COMPILE__)
  return __builtin_amdgcn_mfma_f32_16x16x32_bf16(a, b, c, 0, 0, 0);
#else
  (void)a; (void)b;
  return c;
#endif
}

// async global->LDS DMA, 16B/lane
__device__ __forceinline__ void gld16(const u16* g, u16* l) {
#if defined(__HIP_DEVICE_COMPILE__)
  __builtin_amdgcn_global_load_lds(
      (const __attribute__((address_space(1))) void*)g,
      (__attribute__((address_space(3))) void*)l, 16, 0, 0);
#else
  (void)g; (void)l;
#endif
}

#if defined(__HIP_DEVICE_COMPILE__)
#define SETPRIO(p) __builtin_amdgcn_s_setprio(p)
#else
#define SETPRIO(p)
#endif

// ---------------------------------------------------------------------------
// Kernel 1: fold Wz into Wm (bf16 Wbig + fp32 bbig), blocks 0..191.
// Blocks 192..196: convert the 5 projection weights to bf16 hi/lo planes
// (Wall[plane][pid][o][c], row-major o,c) with LOG2E folded into Wq.
// ---------------------------------------------------------------------------
__global__ __launch_bounds__(256) void fuse_w2_kernel(
    const float* __restrict__ Wz, const float* __restrict__ bz,
    const float* __restrict__ Wm, const float* __restrict__ bm,
    const float* __restrict__ Wq, const float* __restrict__ Wk,
    const float* __restrict__ Wk2, const float* __restrict__ Wv,
    const float* __restrict__ Wv2,
    u16* __restrict__ Wbig, float* __restrict__ bbig, u16* __restrict__ Wall) {
  __shared__ float wrow[128];
  __shared__ float bzs[128];
  int t = threadIdx.x;
  if (blockIdx.x >= 192) {  // weight conversion path
    int pid = blockIdx.x - 192;  // 0..4
    const float* Wsrc = pid == 0 ? Wq : pid == 1 ? Wk : pid == 2 ? Wk2 : pid == 3 ? Wv : Wv2;
    float sc = (pid == 0) ? LOG2E : 1.f;
#pragma unroll
    for (int i = 0; i < 16; ++i) {
      int idx = t * 16 + i;  // 4096 elems
      float w = Wsrc[idx] * sc;
      u16 hu = f2bf(w);
      Wall[pid * 4096 + idx] = hu;
      Wall[5 * 4096 + pid * 4096 + idx] = f2bf(w - bf2f(hu));
    }
    return;
  }
  int o = blockIdx.x;  // 0..191
  if (t < 128) { wrow[t] = Wm[o * 192 + t]; bzs[t] = bz[t]; }
  __syncthreads();
  if (t < 128) {
    float s = 0.f;
#pragma unroll 4
    for (int j = 0; j < 128; ++j) s = fmaf(wrow[j], Wz[j * 128 + t], s);
    Wbig[o * 192 + t] = f2bf(s);
  } else if (t < 192) {
    Wbig[o * 192 + t] = f2bf(Wm[o * 192 + t]);
  } else if (t == 192) {
    float s = bm[o];
    for (int j = 0; j < 128; ++j) s = fmaf(wrow[j], bzs[j], s);
    bbig[o] = s;
  }
}

// ---------------------------------------------------------------------------
// Kernel 2: fused transpose + MFMA projections. (unchanged from R3)
// Output layouts: Q/Kh/Km: [b][n][64] n-major;  V: 16x16x32 B-frag order
//   addr_u16(b,key,c) = b*2^18 + (key>>5)*2048 + (c>>4)*512
//                     + ((key>>3)&3)*128 + (c&15)*8 + (key&7)
// ---------------------------------------------------------------------------
__global__ __launch_bounds__(256) void proj7_kernel(
    const u16* __restrict__ Wall,
    const float* __restrict__ bq, const float* __restrict__ bk,
    const float* __restrict__ bk2, const float* __restrict__ bv,
    const float* __restrict__ bv2,
    const float* __restrict__ h, const float* __restrict__ m,
    u16* __restrict__ Q, u16* __restrict__ Kh, u16* __restrict__ Km,
    u16* __restrict__ Vh, u16* __restrict__ Vm, u16* __restrict__ hT) {
  __shared__ float xs[64][65];
  int blk = blockIdx.x;
  int nt = blk & 63, b = (blk >> 6) & 3, src_m = blk >> 8;
  const float* src = src_m ? m : h;
  int t = threadIdx.x, lane = t & 63, w = t >> 6, col = lane & 15, quad = lane >> 4;
  int n0 = nt * 64;
  {
    int c0 = w * 16, nl = lane;
#pragma unroll
    for (int i = 0; i < 16; ++i)
      xs[c0 + i][nl] = src[((size_t)(b * 64) + c0 + i) * NN + n0 + nl];
  }
  __syncthreads();
  int nloc = w * 16 + col;
  bf16x8 xh[2], xl[2];
#pragma unroll
  for (int half = 0; half < 2; ++half) {
    bf16x8 hh, ll;
#pragma unroll
    for (int j = 0; j < 8; ++j) {
      float x = xs[half * 32 + quad * 8 + j][nloc];
      u16 hu = f2bf(x);
      hh[j] = __builtin_bit_cast(__bf16, hu);
      ll[j] = (__bf16)(x - bf2f(hu));
    }
    xh[half] = hh; xl[half] = ll;
  }
  if (!src_m) {  // hT dump
    int cj = lane & 7, nr = lane >> 3;
#pragma unroll
    for (int it = 0; it < 2; ++it) {
      int n = w * 16 + it * 8 + nr;
      bf16x8 hi8;
#pragma unroll
      for (int i = 0; i < 8; ++i)
        hi8[i] = __builtin_bit_cast(__bf16, f2bf(xs[cj * 8 + i][n]));
      *(bf16x8*)(void*)(hT + ((size_t)b * NN + n0 + n) * 64 + cj * 8) = hi8;
    }
  }
  int glob_n = n0 + nloc;
  auto do_proj = [&](int pid, const float* bias, u16* dstQK, u16* dstV) {
    const u16* Whi = Wall + pid * 4096;
    const u16* Wlo = Wall + 5 * 4096 + pid * 4096;
    float sc = (pid == 0) ? LOG2E : 1.f;
#pragma unroll
    for (int ot = 0; ot < 4; ++ot) {
      size_t wb = (size_t)(ot * 16 + col) * 64 + quad * 8;
      bf16x8 wh0 = *(const bf16x8*)(const void*)(Whi + wb);
      bf16x8 wh1 = *(const bf16x8*)(const void*)(Whi + wb + 32);
      bf16x8 wl0 = *(const bf16x8*)(const void*)(Wlo + wb);
      bf16x8 wl1 = *(const bf16x8*)(const void*)(Wlo + wb + 32);
      float4 b4 = *(const float4*)(bias + ot * 16 + quad * 4);
      f32x4 c = {b4.x * sc, b4.y * sc, b4.z * sc, b4.w * sc};
      c = mfma32(wh0, xh[0], c);
      c = mfma32(wh1, xh[1], c);
      c = mfma32(wh0, xl[0], c);
      c = mfma32(wh1, xl[1], c);
      c = mfma32(wl0, xh[0], c);
      c = mfma32(wl1, xh[1], c);
      if (dstQK) {
        uint2 p;
        p.x = (unsigned)f2bf(c[0]) | ((unsigned)f2bf(c[1]) << 16);
        p.y = (unsigned)f2bf(c[2]) | ((unsigned)f2bf(c[3]) << 16);
        *(uint2*)(void*)(dstQK + ((size_t)b * NN + glob_n) * 64 + ot * 16 + quad * 4) = p;
      } else {
        size_t base = ((size_t)b << 18) + (size_t)(glob_n >> 5) * 2048 + ot * 512 +
                      (size_t)((glob_n >> 3) & 3) * 128 + (glob_n & 7);
#pragma unroll
        for (int r = 0; r < 4; ++r) dstV[base + (quad * 4 + r) * 8] = f2bf(c[r]);
      }
    }
  };
  if (!src_m) {
    do_proj(0, bq, Q, nullptr);
    do_proj(1, bk, Kh, nullptr);
    do_proj(3, bv, nullptr, Vh);
  } else {
    do_proj(2, bk2, Km, nullptr);
    do_proj(4, bv2, nullptr, Vm);
  }
}

// ---------------------------------------------------------------------------
// Kernel 3: flash13 — flash11 geometry + T15 double-pipeline.
// R4 post-mortem: 64 rows/wave (flash12) regressed — VGPR cost halved wave
// supply; flash11's 32 rows/wave + 16 waves/CU is the right occupancy point.
// flash13 keeps that geometry and removes the serial QK->exp->PV chain from
// the wave's matrix-pipe critical path: PV of tile t-1 (independent of St(t))
// is issued between QK(t) and exp(t), so exp's ~150 VALU cyc overlap PV's
// MFMA. V is TRIPLE-buffered so V(t-1) survives STAGE(t+1) (slots differ by
// 2 mod 3). pa is consumed-then-overwritten in place (no extra regs).
// LDS: Kl 2x8KB + Vl 3x8KB = 40KB x 4 blocks/CU = 160KB exact fit.
// ---------------------------------------------------------------------------
__global__ __launch_bounds__(256, 4) void flash13_kernel(
    const u16* __restrict__ Qg, const u16* __restrict__ Khg,
    const u16* __restrict__ Kmg, const u16* __restrict__ Vhg,
    const u16* __restrict__ Vmg, u16* __restrict__ Opart,
    float* __restrict__ Lpart) {
  __shared__ u16 Kl[2][4096];  // 8 KB per buffer: 64 rows x 8 chunks x 16B
  __shared__ u16 Vl[3][4096];  // 8 KB per slot: K=32 B-frag order (tri-buf)
  int blk = blockIdx.x;  // combo = blk&31 -> XCD-local
  int combo = blk & 31, qt = blk >> 5;
  int attn = combo & 1, b = (combo >> 1) & 3, split = combo >> 3;
  const u16* K = (attn ? Kmg : Khg) + (size_t)b * NN * 64;
  const u16* V = (attn ? Vmg : Vhg) + ((size_t)b << 18);  // frag-order base
  int t = threadIdx.x, wave = t >> 6, lane = t & 63, col = lane & 15, quad = lane >> 4;
  int row0 = qt * 128 + wave * 32;  // this wave's 32 query rows

  bf16x8 bq[2][2];
#pragma unroll
  for (int g = 0; g < 2; ++g) {
    const u16* qp = Qg + (size_t)b * NN * 64 + (size_t)(row0 + g * 16 + col) * 64 + quad * 8;
    bq[g][0] = *(const bf16x8*)(const void*)qp;
    bq[g][1] = *(const bf16x8*)(const void*)(qp + 32);
  }

  f32x4 O[2][4];
#pragma unroll
  for (int g = 0; g < 2; ++g)
#pragma unroll
    for (int i = 0; i < 4; ++i) O[g][i] = f32x4{0.f, 0.f, 0.f, 0.f};
  f32x4 Lacc[2];
  Lacc[0] = f32x4{0.f, 0.f, 0.f, 0.f};
  Lacc[1] = f32x4{0.f, 0.f, 0.f, 0.f};
  bf16x8 pa[2][2];  // P-frags of the PREVIOUS tile (pipeline state)
#pragma unroll
  for (int grp = 0; grp < 2; ++grp)
#pragma unroll
    for (int g = 0; g < 2; ++g) pa[grp][g] = bf16x8{};
  const f32x4 minit = {-MFIX, -MFIX, -MFIX, -MFIX};  // shared C-operand
  s16x8 onesv;  // bf16 1.0 x8 (B-operand for the l row-sum MFMA)
#pragma unroll
  for (int i = 0; i < 8; ++i) onesv[i] = (short)0x3F80;
  bf16x8 ones8 = __builtin_bit_cast(bf16x8, onesv);
  int sp = split * 8 + b * 2 + attn;

  const int kbase = split * (NN / SPLITK);
  const int TILES = NN / SPLITK / KTILE;  // 16

  // stage 64-key tile at K0: K into KB (row-permuted + XOR chunk swizzle on
  // the GLOBAL addr, linear LDS dest), V into VB (contiguous, frag order).
#define STAGE(KB, VB, K0)                                                        \
  _Pragma("unroll") for (int jj = 0; jj < 2; ++jj) {                             \
    int p = jj * 256 + t;                                                        \
    int krow_ = p >> 3;                                                          \
    int kj_ = (p & 7) ^ (krow_ & 7);                                             \
    int s5_ = krow_ & 31;                                                        \
    int tr_ = (krow_ & 32) | ((s5_ & 12) << 1) | (((s5_ >> 4) & 1) << 2) | (s5_ & 3); \
    gld16(K + (size_t)((K0) + tr_) * 64 + kj_ * 8, (KB) + p * 8);                \
    gld16(V + (size_t)(K0) * 64 + p * 8, (VB) + p * 8);                          \
  }

  STAGE(&Kl[0][0], &Vl[0][0], kbase);  // prologue: tile 0 -> Kl[0], Vl[0]
  int vs_cur = 0;                      // V slot of tile kt (== kt % 3)

  for (int kt = 0; kt < TILES; ++kt) {
    int cur = kt & 1;
    int vs_nxt = (vs_cur == 2) ? 0 : vs_cur + 1;
    int vs_prv = (vs_cur == 0) ? 2 : vs_cur - 1;
    __syncthreads();  // staging of tile kt complete; prior reads drained
    if (kt + 1 < TILES) {
      STAGE(&Kl[cur ^ 1][0], &Vl[vs_nxt][0], kbase + (kt + 1) * KTILE);
    }
    const u16* Kb = &Kl[cur][0];
    // QK(t): St = K.Q^T - MFIX
    f32x4 St[4][2];
    SETPRIO(1);
#pragma unroll
    for (int nt = 0; nt < 4; ++nt) {
      int row = nt * 16 + col;
      int ph0 = row * 8 + (quad ^ (col & 7));
      int ph1 = row * 8 + ((4 + quad) ^ (col & 7));
      bf16x8 a0 = *(const bf16x8*)(const void*)(Kb + ph0 * 8);
      bf16x8 a1 = *(const bf16x8*)(const void*)(Kb + ph1 * 8);
#pragma unroll
      for (int g = 0; g < 2; ++g) {
        f32x4 acc = mfma32(a0, bq[g][0], minit);
        acc = mfma32(a1, bq[g][1], acc);
        St[nt][g] = acc;
      }
    }
    SETPRIO(0);
    // PV(t-1): independent of St(t) -> matrix pipe busy while exp(t) runs
    if (kt > 0) {
      const u16* vbase = &Vl[vs_prv][0] + lane * 8;
      SETPRIO(1);
#pragma unroll
      for (int grp = 0; grp < 2; ++grp)
#pragma unroll
        for (int ct = 0; ct < 4; ++ct) {
          bf16x8 vf = *(const bf16x8*)(const void*)(vbase + grp * 2048 + ct * 512);
          O[0][ct] = mfma32(pa[grp][0], vf, O[0][ct]);
          O[1][ct] = mfma32(pa[grp][1], vf, O[1][ct]);
        }
      SETPRIO(0);
    }
    // exp/pack(t): overwrite pa in place (WAR after PV consumed it); l-sum
#pragma unroll
    for (int grp = 0; grp < 2; ++grp)
#pragma unroll
      for (int g = 0; g < 2; ++g) {
        s16x8 pf;
#pragma unroll
        for (int r = 0; r < 4; ++r) {
          pf[r] = (short)f2bfs(fexp2(St[2 * grp][g][r]));
          pf[r + 4] = (short)f2bfs(fexp2(St[2 * grp + 1][g][r]));
        }
        bf16x8 p8 = __builtin_bit_cast(bf16x8, pf);
        pa[grp][g] = p8;
        Lacc[g] = mfma32(p8, ones8, Lacc[g]);
      }
    vs_cur = vs_nxt;
  }
#undef STAGE
  {  // drain: PV of the last tile (slot (TILES-1)%3, still intact)
    int vs_prv = (vs_cur == 0) ? 2 : vs_cur - 1;
    const u16* vbase = &Vl[vs_prv][0] + lane * 8;
#pragma unroll
    for (int grp = 0; grp < 2; ++grp)
#pragma unroll
      for (int ct = 0; ct < 4; ++ct) {
        bf16x8 vf = *(const bf16x8*)(const void*)(vbase + grp * 2048 + ct * 512);
        O[0][ct] = mfma32(pa[grp][0], vf, O[0][ct]);
        O[1][ct] = mfma32(pa[grp][1], vf, O[1][ct]);
      }
  }

  // store partials; epilogue does the /l merge.
#pragma unroll
  for (int g = 0; g < 2; ++g) {
#pragma unroll
    for (int ct = 0; ct < 4; ++ct)
#pragma unroll
      for (int r = 0; r < 4; ++r) {
        size_t q = (size_t)row0 + g * 16 + quad * 4 + r;
        Opart[((size_t)sp * NN + q) * 64 + ct * 16 + col] = f2bfs(O[g][ct][r]);
      }
    if (col == 0) {
#pragma unroll
      for (int r = 0; r < 4; ++r)
        Lpart[(size_t)sp * NN + row0 + g * 16 + quad * 4 + r] = Lacc[g][r];
    }
  }
}

// ---------------------------------------------------------------------------
// Kernel 4: fused merge (4-way split) + MFMA epilogue + gating. (unchanged)
// ---------------------------------------------------------------------------
__global__ __launch_bounds__(256) void epi3_kernel(
    const u16* __restrict__ Wb, const float* __restrict__ bb,
    const u16* __restrict__ Opart, const float* __restrict__ Lpart,
    const u16* __restrict__ hT, const float* __restrict__ mglob,
    float* __restrict__ out) {
  int blk = blockIdx.x;  // B*NN/16 = 1024
  int ng = blk * 16;
  int b = ng >> 12;
  int t = threadIdx.x, wave = t >> 6, lane = t & 63, col = lane & 15, quad = lane >> 4;
  int qb = (ng & (NN - 1)) + col;  // per-batch query row
  float Lh = 0.f, Lm = 0.f;
#pragma unroll
  for (int s = 0; s < SPLITK; ++s) {
    Lh += Lpart[(size_t)(s * 8 + b * 2) * NN + qb];
    Lm += Lpart[(size_t)(s * 8 + b * 2 + 1) * NN + qb];
  }
  float invLh = 1.f / Lh;
  float invLm = 1.f / Lm;
  size_t nrow = ((size_t)ng + col) * 64;  // for hT (global n)
  bf16x8 bfr[6];
#define MERGEF(DST, ATTN, OFF, INVL)                                             \
  {                                                                              \
    float s8_[8] = {0.f, 0.f, 0.f, 0.f, 0.f, 0.f, 0.f, 0.f};                     \
    _Pragma("unroll") for (int sp_ = 0; sp_ < SPLITK; ++sp_) {                   \
      const u16* p_ =                                                            \
          Opart + ((size_t)(sp_ * 8 + b * 2 + (ATTN)) * NN + qb) * 64 + (OFF);   \
      bf16x8 a_ = *(const bf16x8*)(const void*)p_;                               \
      _Pragma("unroll") for (int i = 0; i < 8; ++i) s8_[i] += (float)a_[i];      \
    }                                                                            \
    bf16x8 r_;                                                                   \
    _Pragma("unroll") for (int i = 0; i < 8; ++i)                                \
      r_[i] = (__bf16)(s8_[i] * (INVL));                                         \
    DST = r_;                                                                    \
  }
  MERGEF(bfr[0], 0, quad * 8, invLh);
  MERGEF(bfr[1], 0, 32 + quad * 8, invLh);
  MERGEF(bfr[2], 1, quad * 8, invLm);
  MERGEF(bfr[3], 1, 32 + quad * 8, invLm);
#undef MERGEF
  bfr[4] = *(const bf16x8*)(const void*)(hT + nrow + quad * 8);
  bfr[5] = *(const bf16x8*)(const void*)(hT + nrow + 32 + quad * 8);
  f32x4 acc[3];
#pragma unroll
  for (int j = 0; j < 3; ++j) {
    int mt = wave + j * 4;
#pragma unroll
    for (int r = 0; r < 4; ++r) acc[j][r] = bb[mt * 16 + quad * 4 + r];
  }
#pragma unroll
  for (int ks = 0; ks < 6; ++ks) {
#pragma unroll
    for (int j = 0; j < 3; ++j) {
      int mt = wave + j * 4;
      bf16x8 af = *(const bf16x8*)(const void*)(Wb + (size_t)(mt * 16 + col) * 192 + ks * 32 + quad * 8);
      acc[j] = mfma32(af, bfr[ks], acc[j]);
    }
  }
  int nloc = (ng & (NN - 1)) + col;
#pragma unroll
  for (int r = 0; r < 4; ++r) {
    int o = wave * 16 + quad * 4 + r;
    float mo = acc[0][r], mgt = acc[1][r], mi = acc[2][r];
    float si = 1.f / (1.f + fexp2(-mi * LOG2E));
    float tg = 1.f - 2.f / (fexp2(2.f * LOG2E * mgt) + 1.f);
    float mv = mglob[(size_t)(b * 64 + o) * NN + nloc];
    float nm = (1.f - si) * mv + si * tg;
    float nh = nm / (1.f + fexp2(-mo * LOG2E));
    out[(size_t)(b * 64 + o) * NN + nloc] = nh;
    out[(size_t)BN * 64 * NN + (size_t)(b * 64 + o) * NN + nloc] = nm;
  }
}

extern "C" void kernel_launch(void* const* d_in, const int* in_sizes, int n_in,
                              void* d_out, int out_size, void* d_ws, size_t ws_size,
                              hipStream_t stream) {
  const float* h = (const float*)d_in[0];
  const float* m = (const float*)d_in[1];
  const float* Wq = (const float*)d_in[2];
  const float* bq = (const float*)d_in[3];
  const float* Wk = (const float*)d_in[4];
  const float* bk = (const float*)d_in[5];
  const float* Wk2 = (const float*)d_in[6];
  const float* bk2 = (const float*)d_in[7];
  const float* Wv = (const float*)d_in[8];
  const float* bv = (const float*)d_in[9];
  const float* Wv2 = (const float*)d_in[10];
  const float* bv2 = (const float*)d_in[11];
  const float* Wz = (const float*)d_in[12];
  const float* bz = (const float*)d_in[13];
  const float* Wm = (const float*)d_in[14];
  const float* bm = (const float*)d_in[15];
  float* out = (float*)d_out;

  size_t off = 0;
  auto alloc = [&](size_t bytes) {
    void* p = (char*)d_ws + off;
    off += (bytes + 255) & ~(size_t)255;
    return p;
  };
  const size_t bn64 = (size_t)BN * NN * 64;
  u16* Q  = (u16*)alloc(bn64 * 2);
  u16* Kh = (u16*)alloc(bn64 * 2);
  u16* Km = (u16*)alloc(bn64 * 2);
  u16* Vh = (u16*)alloc(bn64 * 2);
  u16* Vm = (u16*)alloc(bn64 * 2);
  u16* hT = (u16*)alloc(bn64 * 2);
  u16* Opart = (u16*)alloc((size_t)SPLITK * 8 * NN * 64 * 2);
  float* Lpart = (float*)alloc((size_t)SPLITK * 8 * NN * 4);
  u16* Wbigbf = (u16*)alloc(192 * 192 * 2);
  float* bbig = (float*)alloc(192 * 4);
  u16* Wall = (u16*)alloc((size_t)2 * 5 * 4096 * 2);  // hi/lo planes
  (void)ws_size; (void)in_sizes; (void)n_in; (void)out_size;

  fuse_w2_kernel<<<197, 256, 0, stream>>>(Wz, bz, Wm, bm, Wq, Wk, Wk2, Wv, Wv2,
                                          Wbigbf, bbig, Wall);
  proj7_kernel<<<2 * BN * 64, 256, 0, stream>>>(Wall, bq, bk, bk2, bv, bv2, h, m,
                                                Q, Kh, Km, Vh, Vm, hT);
  flash13_kernel<<<32 * 32, 256, 0, stream>>>(Q, Kh, Km, Vh, Vm, Opart, Lpart);
  epi3_kernel<<<(BN * NN) / 16, 256, 0, stream>>>(Wbigbf, bbig, Opart, Lpart, hT, m, out);
}

// Round 6
// 167.070 us; speedup vs baseline: 1.0193x; 1.0193x over previous
//
#include <hip/hip_runtime.h>

#define BN 4
#define NN 4096
#define SPLITK 4
#define KTILE 64
#define LOG2E 1.44269504f
#define MFIX 36.0f

typedef __attribute__((ext_vector_type(8))) __bf16 bf16x8;
typedef __attribute__((ext_vector_type(8))) short s16x8;
typedef __attribute__((ext_vector_type(4))) float f32x4;
typedef unsigned short u16;

__device__ __forceinline__ u16 f2bf(float x) {  // manual RNE
  unsigned int u = __builtin_bit_cast(unsigned int, x);
  u = (u + 0x7fffu + ((u >> 16) & 1u)) >> 16;
  return (u16)u;
}
__device__ __forceinline__ u16 f2bfs(float x) {  // hw cvt path
  __bf16 b = (__bf16)x;
  return __builtin_bit_cast(u16, b);
}
__device__ __forceinline__ float bf2f(u16 s) {
  unsigned int u = ((unsigned int)s) << 16;
  return __builtin_bit_cast(float, u);
}

// raw v_exp_f32 (no denormal-fixup sequence). Inputs in [-100, 0].
__device__ __forceinline__ float fexp2(float x) {
#if defined(__HIP_DEVICE_COMPILE__) && __has_builtin(__builtin_amdgcn_exp2f)
  return __builtin_amdgcn_exp2f(x);
#else
  return __builtin_exp2f(x);
#endif
}

// v_mfma_f32_16x16x32_bf16 (native K=32 pipe)
__device__ __forceinline__ f32x4 mfma32(bf16x8 a, bf16x8 b, f32x4 c) {
#if defined(__HIP_DEVICE_COMPILE__)
  return __builtin_amdgcn_mfma_f32_16x16x32_bf16(a, b, c, 0, 0, 0);
#else
  (void)a; (void)b;
  return c;
#endif
}

// async global->LDS DMA, 16B/lane
__device__ __forceinline__ void gld16(const u16* g, u16* l) {
#if defined(__HIP_DEVICE_COMPILE__)
  __builtin_amdgcn_global_load_lds(
      (const __attribute__((address_space(1))) void*)g,
      (__attribute__((address_space(3))) void*)l, 16, 0, 0);
#else
  (void)g; (void)l;
#endif
}

#if defined(__HIP_DEVICE_COMPILE__)
#define SETPRIO(p) __builtin_amdgcn_s_setprio(p)
#else
#define SETPRIO(p)
#endif

// ---------------------------------------------------------------------------
// Kernel 1: fold Wz into Wm (bf16 Wbig + fp32 bbig), blocks 0..191.
// Blocks 192..196: convert the 5 projection weights to bf16 hi/lo planes
// (Wall[plane][pid][o][c], row-major o,c) with LOG2E folded into Wq.
// ---------------------------------------------------------------------------
__global__ __launch_bounds__(256) void fuse_w2_kernel(
    const float* __restrict__ Wz, const float* __restrict__ bz,
    const float* __restrict__ Wm, const float* __restrict__ bm,
    const float* __restrict__ Wq, const float* __restrict__ Wk,
    const float* __restrict__ Wk2, const float* __restrict__ Wv,
    const float* __restrict__ Wv2,
    u16* __restrict__ Wbig, float* __restrict__ bbig, u16* __restrict__ Wall) {
  __shared__ float wrow[128];
  __shared__ float bzs[128];
  int t = threadIdx.x;
  if (blockIdx.x >= 192) {  // weight conversion path
    int pid = blockIdx.x - 192;  // 0..4
    const float* Wsrc = pid == 0 ? Wq : pid == 1 ? Wk : pid == 2 ? Wk2 : pid == 3 ? Wv : Wv2;
    float sc = (pid == 0) ? LOG2E : 1.f;
#pragma unroll
    for (int i = 0; i < 16; ++i) {
      int idx = t * 16 + i;  // 4096 elems
      float w = Wsrc[idx] * sc;
      u16 hu = f2bf(w);
      Wall[pid * 4096 + idx] = hu;
      Wall[5 * 4096 + pid * 4096 + idx] = f2bf(w - bf2f(hu));
    }
    return;
  }
  int o = blockIdx.x;  // 0..191
  if (t < 128) { wrow[t] = Wm[o * 192 + t]; bzs[t] = bz[t]; }
  __syncthreads();
  if (t < 128) {
    float s = 0.f;
#pragma unroll 4
    for (int j = 0; j < 128; ++j) s = fmaf(wrow[j], Wz[j * 128 + t], s);
    Wbig[o * 192 + t] = f2bf(s);
  } else if (t < 192) {
    Wbig[o * 192 + t] = f2bf(Wm[o * 192 + t]);
  } else if (t == 192) {
    float s = bm[o];
    for (int j = 0; j < 128; ++j) s = fmaf(wrow[j], bzs[j], s);
    bbig[o] = s;
  }
}

// ---------------------------------------------------------------------------
// Kernel 2: fused transpose + MFMA projections. (unchanged from R3)
// Output layouts: Q/Kh/Km: [b][n][64] n-major;  V: 16x16x32 B-frag order
//   addr_u16(b,key,c) = b*2^18 + (key>>5)*2048 + (c>>4)*512
//                     + ((key>>3)&3)*128 + (c&15)*8 + (key&7)
// ---------------------------------------------------------------------------
__global__ __launch_bounds__(256) void proj7_kernel(
    const u16* __restrict__ Wall,
    const float* __restrict__ bq, const float* __restrict__ bk,
    const float* __restrict__ bk2, const float* __restrict__ bv,
    const float* __restrict__ bv2,
    const float* __restrict__ h, const float* __restrict__ m,
    u16* __restrict__ Q, u16* __restrict__ Kh, u16* __restrict__ Km,
    u16* __restrict__ Vh, u16* __restrict__ Vm, u16* __restrict__ hT) {
  __shared__ float xs[64][65];
  int blk = blockIdx.x;
  int nt = blk & 63, b = (blk >> 6) & 3, src_m = blk >> 8;
  const float* src = src_m ? m : h;
  int t = threadIdx.x, lane = t & 63, w = t >> 6, col = lane & 15, quad = lane >> 4;
  int n0 = nt * 64;
  {
    int c0 = w * 16, nl = lane;
#pragma unroll
    for (int i = 0; i < 16; ++i)
      xs[c0 + i][nl] = src[((size_t)(b * 64) + c0 + i) * NN + n0 + nl];
  }
  __syncthreads();
  int nloc = w * 16 + col;
  bf16x8 xh[2], xl[2];
#pragma unroll
  for (int half = 0; half < 2; ++half) {
    bf16x8 hh, ll;
#pragma unroll
    for (int j = 0; j < 8; ++j) {
      float x = xs[half * 32 + quad * 8 + j][nloc];
      u16 hu = f2bf(x);
      hh[j] = __builtin_bit_cast(__bf16, hu);
      ll[j] = (__bf16)(x - bf2f(hu));
    }
    xh[half] = hh; xl[half] = ll;
  }
  if (!src_m) {  // hT dump
    int cj = lane & 7, nr = lane >> 3;
#pragma unroll
    for (int it = 0; it < 2; ++it) {
      int n = w * 16 + it * 8 + nr;
      bf16x8 hi8;
#pragma unroll
      for (int i = 0; i < 8; ++i)
        hi8[i] = __builtin_bit_cast(__bf16, f2bf(xs[cj * 8 + i][n]));
      *(bf16x8*)(void*)(hT + ((size_t)b * NN + n0 + n) * 64 + cj * 8) = hi8;
    }
  }
  int glob_n = n0 + nloc;
  auto do_proj = [&](int pid, const float* bias, u16* dstQK, u16* dstV) {
    const u16* Whi = Wall + pid * 4096;
    const u16* Wlo = Wall + 5 * 4096 + pid * 4096;
    float sc = (pid == 0) ? LOG2E : 1.f;
#pragma unroll
    for (int ot = 0; ot < 4; ++ot) {
      size_t wb = (size_t)(ot * 16 + col) * 64 + quad * 8;
      bf16x8 wh0 = *(const bf16x8*)(const void*)(Whi + wb);
      bf16x8 wh1 = *(const bf16x8*)(const void*)(Whi + wb + 32);
      bf16x8 wl0 = *(const bf16x8*)(const void*)(Wlo + wb);
      bf16x8 wl1 = *(const bf16x8*)(const void*)(Wlo + wb + 32);
      float4 b4 = *(const float4*)(bias + ot * 16 + quad * 4);
      f32x4 c = {b4.x * sc, b4.y * sc, b4.z * sc, b4.w * sc};
      c = mfma32(wh0, xh[0], c);
      c = mfma32(wh1, xh[1], c);
      c = mfma32(wh0, xl[0], c);
      c = mfma32(wh1, xl[1], c);
      c = mfma32(wl0, xh[0], c);
      c = mfma32(wl1, xh[1], c);
      if (dstQK) {
        uint2 p;
        p.x = (unsigned)f2bf(c[0]) | ((unsigned)f2bf(c[1]) << 16);
        p.y = (unsigned)f2bf(c[2]) | ((unsigned)f2bf(c[3]) << 16);
        *(uint2*)(void*)(dstQK + ((size_t)b * NN + glob_n) * 64 + ot * 16 + quad * 4) = p;
      } else {
        size_t base = ((size_t)b << 18) + (size_t)(glob_n >> 5) * 2048 + ot * 512 +
                      (size_t)((glob_n >> 3) & 3) * 128 + (glob_n & 7);
#pragma unroll
        for (int r = 0; r < 4; ++r) dstV[base + (quad * 4 + r) * 8] = f2bf(c[r]);
      }
    }
  };
  if (!src_m) {
    do_proj(0, bq, Q, nullptr);
    do_proj(1, bk, Kh, nullptr);
    do_proj(3, bv, nullptr, Vh);
  } else {
    do_proj(2, bk2, Km, nullptr);
    do_proj(4, bv2, nullptr, Vm);
  }
}

// ---------------------------------------------------------------------------
// Kernel 3: flash14 — T15 pipeline, PV-FIRST ordering (spill fix of flash13).
// R5 post-mortem: flash13 put PV(t-1) between QK(t) and exp(t) -> St (32
// regs) live across the PV cluster -> spill (VGPR 64 + 9MB scratch traffic).
// flash14 orders: barrier -> STAGE(t+1) -> PV(t-1) -> QK(t) -> exp(t).
// pa is consumed by PV before QK creates St; St dies into exp immediately.
// Peak live ~116 regs < 128 (4 waves/SIMD). The wave still issues a
// contiguous 24-MFMA burst (PV+QK) then runs exp on the VALU while other
// waves' bursts keep the matrix pipe fed. V tri-buffered as in flash13.
// ---------------------------------------------------------------------------
__global__ __launch_bounds__(256, 4) void flash14_kernel(
    const u16* __restrict__ Qg, const u16* __restrict__ Khg,
    const u16* __restrict__ Kmg, const u16* __restrict__ Vhg,
    const u16* __restrict__ Vmg, u16* __restrict__ Opart,
    float* __restrict__ Lpart) {
  __shared__ u16 Kl[2][4096];  // 8 KB per buffer: 64 rows x 8 chunks x 16B
  __shared__ u16 Vl[3][4096];  // 8 KB per slot: K=32 B-frag order (tri-buf)
  int blk = blockIdx.x;  // combo = blk&31 -> XCD-local
  int combo = blk & 31, qt = blk >> 5;
  int attn = combo & 1, b = (combo >> 1) & 3, split = combo >> 3;
  const u16* K = (attn ? Kmg : Khg) + (size_t)b * NN * 64;
  const u16* V = (attn ? Vmg : Vhg) + ((size_t)b << 18);  // frag-order base
  int t = threadIdx.x, wave = t >> 6, lane = t & 63, col = lane & 15, quad = lane >> 4;
  int row0 = qt * 128 + wave * 32;  // this wave's 32 query rows

  bf16x8 bq[2][2];
#pragma unroll
  for (int g = 0; g < 2; ++g) {
    const u16* qp = Qg + (size_t)b * NN * 64 + (size_t)(row0 + g * 16 + col) * 64 + quad * 8;
    bq[g][0] = *(const bf16x8*)(const void*)qp;
    bq[g][1] = *(const bf16x8*)(const void*)(qp + 32);
  }

  f32x4 O[2][4];
#pragma unroll
  for (int g = 0; g < 2; ++g)
#pragma unroll
    for (int i = 0; i < 4; ++i) O[g][i] = f32x4{0.f, 0.f, 0.f, 0.f};
  f32x4 Lacc[2];
  Lacc[0] = f32x4{0.f, 0.f, 0.f, 0.f};
  Lacc[1] = f32x4{0.f, 0.f, 0.f, 0.f};
  bf16x8 pa[2][2];  // P-frags of the PREVIOUS tile (pipeline state)
#pragma unroll
  for (int grp = 0; grp < 2; ++grp)
#pragma unroll
    for (int g = 0; g < 2; ++g) pa[grp][g] = bf16x8{};
  const f32x4 minit = {-MFIX, -MFIX, -MFIX, -MFIX};  // shared C-operand
  s16x8 onesv;  // bf16 1.0 x8 (B-operand for the l row-sum MFMA)
#pragma unroll
  for (int i = 0; i < 8; ++i) onesv[i] = (short)0x3F80;
  bf16x8 ones8 = __builtin_bit_cast(bf16x8, onesv);
  int sp = split * 8 + b * 2 + attn;

  const int kbase = split * (NN / SPLITK);
  const int TILES = NN / SPLITK / KTILE;  // 16

  // stage 64-key tile at K0: K into KB (row-permuted + XOR chunk swizzle on
  // the GLOBAL addr, linear LDS dest), V into VB (contiguous, frag order).
#define STAGE(KB, VB, K0)                                                        \
  _Pragma("unroll") for (int jj = 0; jj < 2; ++jj) {                             \
    int p = jj * 256 + t;                                                        \
    int krow_ = p >> 3;                                                          \
    int kj_ = (p & 7) ^ (krow_ & 7);                                             \
    int s5_ = krow_ & 31;                                                        \
    int tr_ = (krow_ & 32) | ((s5_ & 12) << 1) | (((s5_ >> 4) & 1) << 2) | (s5_ & 3); \
    gld16(K + (size_t)((K0) + tr_) * 64 + kj_ * 8, (KB) + p * 8);                \
    gld16(V + (size_t)(K0) * 64 + p * 8, (VB) + p * 8);                          \
  }

  STAGE(&Kl[0][0], &Vl[0][0], kbase);  // prologue: tile 0 -> Kl[0], Vl[0]
  int vs_cur = 0;                      // V slot of tile kt (== kt % 3)

  for (int kt = 0; kt < TILES; ++kt) {
    int cur = kt & 1;
    int vs_nxt = (vs_cur == 2) ? 0 : vs_cur + 1;
    int vs_prv = (vs_cur == 0) ? 2 : vs_cur - 1;
    __syncthreads();  // staging of tile kt complete; prior reads drained
    if (kt + 1 < TILES) {
      STAGE(&Kl[cur ^ 1][0], &Vl[vs_nxt][0], kbase + (kt + 1) * KTILE);
    }
    // PV(t-1) FIRST: consumes pa before QK creates St (register discipline);
    // matrix pipe gets a contiguous PV+QK burst, then exp runs on the VALU.
    if (kt > 0) {
      const u16* vbase = &Vl[vs_prv][0] + lane * 8;
      SETPRIO(1);
#pragma unroll
      for (int grp = 0; grp < 2; ++grp)
#pragma unroll
        for (int ct = 0; ct < 4; ++ct) {
          bf16x8 vf = *(const bf16x8*)(const void*)(vbase + grp * 2048 + ct * 512);
          O[0][ct] = mfma32(pa[grp][0], vf, O[0][ct]);
          O[1][ct] = mfma32(pa[grp][1], vf, O[1][ct]);
        }
      SETPRIO(0);
    }
    const u16* Kb = &Kl[cur][0];
    // QK(t): St = K.Q^T - MFIX
    f32x4 St[4][2];
    SETPRIO(1);
#pragma unroll
    for (int nt = 0; nt < 4; ++nt) {
      int row = nt * 16 + col;
      int ph0 = row * 8 + (quad ^ (col & 7));
      int ph1 = row * 8 + ((4 + quad) ^ (col & 7));
      bf16x8 a0 = *(const bf16x8*)(const void*)(Kb + ph0 * 8);
      bf16x8 a1 = *(const bf16x8*)(const void*)(Kb + ph1 * 8);
#pragma unroll
      for (int g = 0; g < 2; ++g) {
        f32x4 acc = mfma32(a0, bq[g][0], minit);
        acc = mfma32(a1, bq[g][1], acc);
        St[nt][g] = acc;
      }
    }
    SETPRIO(0);
    // exp/pack(t): pa already consumed (WAR safe); l-sum via ones-MFMA
#pragma unroll
    for (int grp = 0; grp < 2; ++grp)
#pragma unroll
      for (int g = 0; g < 2; ++g) {
        s16x8 pf;
#pragma unroll
        for (int r = 0; r < 4; ++r) {
          pf[r] = (short)f2bfs(fexp2(St[2 * grp][g][r]));
          pf[r + 4] = (short)f2bfs(fexp2(St[2 * grp + 1][g][r]));
        }
        bf16x8 p8 = __builtin_bit_cast(bf16x8, pf);
        pa[grp][g] = p8;
        Lacc[g] = mfma32(p8, ones8, Lacc[g]);
      }
    vs_cur = vs_nxt;
  }
#undef STAGE
  {  // drain: PV of the last tile (slot (TILES-1)%3, still intact)
    int vs_prv = (vs_cur == 0) ? 2 : vs_cur - 1;
    const u16* vbase = &Vl[vs_prv][0] + lane * 8;
#pragma unroll
    for (int grp = 0; grp < 2; ++grp)
#pragma unroll
      for (int ct = 0; ct < 4; ++ct) {
        bf16x8 vf = *(const bf16x8*)(const void*)(vbase + grp * 2048 + ct * 512);
        O[0][ct] = mfma32(pa[grp][0], vf, O[0][ct]);
        O[1][ct] = mfma32(pa[grp][1], vf, O[1][ct]);
      }
  }

  // store partials; epilogue does the /l merge.
#pragma unroll
  for (int g = 0; g < 2; ++g) {
#pragma unroll
    for (int ct = 0; ct < 4; ++ct)
#pragma unroll
      for (int r = 0; r < 4; ++r) {
        size_t q = (size_t)row0 + g * 16 + quad * 4 + r;
        Opart[((size_t)sp * NN + q) * 64 + ct * 16 + col] = f2bfs(O[g][ct][r]);
      }
    if (col == 0) {
#pragma unroll
      for (int r = 0; r < 4; ++r)
        Lpart[(size_t)sp * NN + row0 + g * 16 + quad * 4 + r] = Lacc[g][r];
    }
  }
}

// ---------------------------------------------------------------------------
// Kernel 4: fused merge (4-way split) + MFMA epilogue + gating. (unchanged)
// ---------------------------------------------------------------------------
__global__ __launch_bounds__(256) void epi3_kernel(
    const u16* __restrict__ Wb, const float* __restrict__ bb,
    const u16* __restrict__ Opart, const float* __restrict__ Lpart,
    const u16* __restrict__ hT, const float* __restrict__ mglob,
    float* __restrict__ out) {
  int blk = blockIdx.x;  // B*NN/16 = 1024
  int ng = blk * 16;
  int b = ng >> 12;
  int t = threadIdx.x, wave = t >> 6, lane = t & 63, col = lane & 15, quad = lane >> 4;
  int qb = (ng & (NN - 1)) + col;  // per-batch query row
  float Lh = 0.f, Lm = 0.f;
#pragma unroll
  for (int s = 0; s < SPLITK; ++s) {
    Lh += Lpart[(size_t)(s * 8 + b * 2) * NN + qb];
    Lm += Lpart[(size_t)(s * 8 + b * 2 + 1) * NN + qb];
  }
  float invLh = 1.f / Lh;
  float invLm = 1.f / Lm;
  size_t nrow = ((size_t)ng + col) * 64;  // for hT (global n)
  bf16x8 bfr[6];
#define MERGEF(DST, ATTN, OFF, INVL)                                             \
  {                                                                              \
    float s8_[8] = {0.f, 0.f, 0.f, 0.f, 0.f, 0.f, 0.f, 0.f};                     \
    _Pragma("unroll") for (int sp_ = 0; sp_ < SPLITK; ++sp_) {                   \
      const u16* p_ =                                                            \
          Opart + ((size_t)(sp_ * 8 + b * 2 + (ATTN)) * NN + qb) * 64 + (OFF);   \
      bf16x8 a_ = *(const bf16x8*)(const void*)p_;                               \
      _Pragma("unroll") for (int i = 0; i < 8; ++i) s8_[i] += (float)a_[i];      \
    }                                                                            \
    bf16x8 r_;                                                                   \
    _Pragma("unroll") for (int i = 0; i < 8; ++i)                                \
      r_[i] = (__bf16)(s8_[i] * (INVL));                                         \
    DST = r_;                                                                    \
  }
  MERGEF(bfr[0], 0, quad * 8, invLh);
  MERGEF(bfr[1], 0, 32 + quad * 8, invLh);
  MERGEF(bfr[2], 1, quad * 8, invLm);
  MERGEF(bfr[3], 1, 32 + quad * 8, invLm);
#undef MERGEF
  bfr[4] = *(const bf16x8*)(const void*)(hT + nrow + quad * 8);
  bfr[5] = *(const bf16x8*)(const void*)(hT + nrow + 32 + quad * 8);
  f32x4 acc[3];
#pragma unroll
  for (int j = 0; j < 3; ++j) {
    int mt = wave + j * 4;
#pragma unroll
    for (int r = 0; r < 4; ++r) acc[j][r] = bb[mt * 16 + quad * 4 + r];
  }
#pragma unroll
  for (int ks = 0; ks < 6; ++ks) {
#pragma unroll
    for (int j = 0; j < 3; ++j) {
      int mt = wave + j * 4;
      bf16x8 af = *(const bf16x8*)(const void*)(Wb + (size_t)(mt * 16 + col) * 192 + ks * 32 + quad * 8);
      acc[j] = mfma32(af, bfr[ks], acc[j]);
    }
  }
  int nloc = (ng & (NN - 1)) + col;
#pragma unroll
  for (int r = 0; r < 4; ++r) {
    int o = wave * 16 + quad * 4 + r;
    float mo = acc[0][r], mgt = acc[1][r], mi = acc[2][r];
    float si = 1.f / (1.f + fexp2(-mi * LOG2E));
    float tg = 1.f - 2.f / (fexp2(2.f * LOG2E * mgt) + 1.f);
    float mv = mglob[(size_t)(b * 64 + o) * NN + nloc];
    float nm = (1.f - si) * mv + si * tg;
    float nh = nm / (1.f + fexp2(-mo * LOG2E));
    out[(size_t)(b * 64 + o) * NN + nloc] = nh;
    out[(size_t)BN * 64 * NN + (size_t)(b * 64 + o) * NN + nloc] = nm;
  }
}

extern "C" void kernel_launch(void* const* d_in, const int* in_sizes, int n_in,
                              void* d_out, int out_size, void* d_ws, size_t ws_size,
                              hipStream_t stream) {
  const float* h = (const float*)d_in[0];
  const float* m = (const float*)d_in[1];
  const float* Wq = (const float*)d_in[2];
  const float* bq = (const float*)d_in[3];
  const float* Wk = (const float*)d_in[4];
  const float* bk = (const float*)d_in[5];
  const float* Wk2 = (const float*)d_in[6];
  const float* bk2 = (const float*)d_in[7];
  const float* Wv = (const float*)d_in[8];
  const float* bv = (const float*)d_in[9];
  const float* Wv2 = (const float*)d_in[10];
  const float* bv2 = (const float*)d_in[11];
  const float* Wz = (const float*)d_in[12];
  const float* bz = (const float*)d_in[13];
  const float* Wm = (const float*)d_in[14];
  const float* bm = (const float*)d_in[15];
  float* out = (float*)d_out;

  size_t off = 0;
  auto alloc = [&](size_t bytes) {
    void* p = (char*)d_ws + off;
    off += (bytes + 255) & ~(size_t)255;
    return p;
  };
  const size_t bn64 = (size_t)BN * NN * 64;
  u16* Q  = (u16*)alloc(bn64 * 2);
  u16* Kh = (u16*)alloc(bn64 * 2);
  u16* Km = (u16*)alloc(bn64 * 2);
  u16* Vh = (u16*)alloc(bn64 * 2);
  u16* Vm = (u16*)alloc(bn64 * 2);
  u16* hT = (u16*)alloc(bn64 * 2);
  u16* Opart = (u16*)alloc((size_t)SPLITK * 8 * NN * 64 * 2);
  float* Lpart = (float*)alloc((size_t)SPLITK * 8 * NN * 4);
  u16* Wbigbf = (u16*)alloc(192 * 192 * 2);
  float* bbig = (float*)alloc(192 * 4);
  u16* Wall = (u16*)alloc((size_t)2 * 5 * 4096 * 2);  // hi/lo planes
  (void)ws_size; (void)in_sizes; (void)n_in; (void)out_size;

  fuse_w2_kernel<<<197, 256, 0, stream>>>(Wz, bz, Wm, bm, Wq, Wk, Wk2, Wv, Wv2,
                                          Wbigbf, bbig, Wall);
  proj7_kernel<<<2 * BN * 64, 256, 0, stream>>>(Wall, bq, bk, bk2, bv, bv2, h, m,
                                                Q, Kh, Km, Vh, Vm, hT);
  flash14_kernel<<<32 * 32, 256, 0, stream>>>(Q, Kh, Km, Vh, Vm, Opart, Lpart);
  epi3_kernel<<<(BN * NN) / 16, 256, 0, stream>>>(Wbigbf, bbig, Opart, Lpart, hT, m, out);
}